// Round 15
// baseline (241.369 us; speedup 1.0000x reference)
//
#include <hip/hip_runtime.h>
#include <hip/hip_fp16.h>

#define NN 50000
#define EE 800000
#define ETOT (EE + NN)     // edges + self-loops
#define NEG 0.2f
#define NG 64

__device__ __forceinline__ float lrelu(float x) { return x > 0.f ? x : NEG * x; }
__device__ __forceinline__ unsigned fenc(float f) {
    unsigned u = __float_as_uint(f);
    return (u & 0x80000000u) ? ~u : (u | 0x80000000u);
}
__device__ __forceinline__ float fdec(unsigned u) {
    return (u & 0x80000000u) ? __uint_as_float(u & 0x7fffffffu)
                             : __uint_as_float(~u);
}

// ---------- GEMM1: h1 = x @ W1 (f16 storage); al1_s/al1_d fused (f32 exact) ----------
__global__ __launch_bounds__(256) void gemm1(const float* __restrict__ x,
                                             const float* __restrict__ W1,
                                             const float* __restrict__ a1s,
                                             const float* __restrict__ a1d,
                                             __half* __restrict__ h1h,
                                             float* __restrict__ al1s,
                                             float* __restrict__ al1d) {
    __shared__ float sx[64][132];   // row stride 528B (16B-aligned)
    __shared__ float sW[64][64];
    const int t = threadIdx.x;
    const int row0 = blockIdx.x * 64;
    for (int i = t * 4; i < 64 * 128; i += 256 * 4) {
        int r = i >> 7, k = i & 127;
        int gr = row0 + r;
        float4 v = make_float4(0.f, 0.f, 0.f, 0.f);
        if (gr < NN) v = *(const float4*)&x[(size_t)gr * 128 + k];
        *(float4*)&sx[r][k] = v;
    }
    float acc[4][4] = {{0.f, 0.f, 0.f, 0.f}};
    const int c4 = (t & 15) * 4;
    const int r4 = (t >> 4) * 4;
    for (int k0 = 0; k0 < 128; k0 += 64) {
        __syncthreads();
        for (int i = t * 4; i < 64 * 64; i += 256 * 4) {
            int kk = i >> 6, c = i & 63;
            *(float4*)&sW[kk][c] = *(const float4*)&W1[(size_t)(k0 + kk) * 64 + c];
        }
        __syncthreads();
#pragma unroll 4
        for (int kk = 0; kk < 64; kk += 4) {
            float4 wv0 = *(float4*)&sW[kk + 0][c4];
            float4 wv1 = *(float4*)&sW[kk + 1][c4];
            float4 wv2 = *(float4*)&sW[kk + 2][c4];
            float4 wv3 = *(float4*)&sW[kk + 3][c4];
#pragma unroll
            for (int r = 0; r < 4; ++r) {
                float4 xv = *(const float4*)&sx[r4 + r][k0 + kk];
                acc[r][0] += xv.x * wv0.x; acc[r][1] += xv.x * wv0.y; acc[r][2] += xv.x * wv0.z; acc[r][3] += xv.x * wv0.w;
                acc[r][0] += xv.y * wv1.x; acc[r][1] += xv.y * wv1.y; acc[r][2] += xv.y * wv1.z; acc[r][3] += xv.y * wv1.w;
                acc[r][0] += xv.z * wv2.x; acc[r][1] += xv.z * wv2.y; acc[r][2] += xv.z * wv2.z; acc[r][3] += xv.z * wv2.w;
                acc[r][0] += xv.w * wv3.x; acc[r][1] += xv.w * wv3.y; acc[r][2] += xv.w * wv3.z; acc[r][3] += xv.w * wv3.w;
            }
        }
    }
    const float4 asv = *(const float4*)&a1s[c4];
    const float4 adv = *(const float4*)&a1d[c4];
#pragma unroll
    for (int r = 0; r < 4; ++r) {
        int row = row0 + r4 + r;
        float ps = acc[r][0] * asv.x + acc[r][1] * asv.y + acc[r][2] * asv.z + acc[r][3] * asv.w;
        float pd = acc[r][0] * adv.x + acc[r][1] * adv.y + acc[r][2] * adv.z + acc[r][3] * adv.w;
        ps += __shfl_xor(ps, 1);     // pair covers one head (8 channels)
        pd += __shfl_xor(pd, 1);
        if (row < NN) {
            __half2 h01 = __floats2half2_rn(acc[r][0], acc[r][1]);
            __half2 h23 = __floats2half2_rn(acc[r][2], acc[r][3]);
            float2 pk;
            *(__half2*)&pk.x = h01;
            *(__half2*)&pk.y = h23;
            *(float2*)&h1h[(size_t)row * 64 + c4] = pk;   // 8B store
            if ((t & 1) == 0) {
                int h = (t & 15) >> 1;
                al1s[row * 8 + h] = ps;
                al1d[row * 8 + h] = pd;
            }
        }
    }
}

// ---------- global per-head max of al1s (standalone; 784 spread atomics) ----------
__global__ __launch_bounds__(256) void maxal1(const float* __restrict__ al1s,
                                              unsigned* __restrict__ gmax1) {
    const int t = blockIdx.x * 256 + threadIdx.x;
    const int h = t & 7;
    float m = -1e30f;
    for (int i = t; i < NN * 8; i += 98 * 256) m = fmaxf(m, al1s[i]);
    m = fmaxf(m, __shfl_xor(m, 8));
    m = fmaxf(m, __shfl_xor(m, 16));
    m = fmaxf(m, __shfl_xor(m, 32));
    if ((threadIdx.x & 63) < 8) atomicMax(&gmax1[h], fenc(m));
}

// ---------- CSR build ----------
__global__ __launch_bounds__(256) void hist(const int* __restrict__ ei,
                                            int* __restrict__ deg,
                                            int* __restrict__ epos) {
    int e = blockIdx.x * 256 + threadIdx.x;
    if (e >= ETOT) return;
    int d = (e < EE) ? ei[EE + e] : e - EE;
    epos[e] = atomicAdd(&deg[d], 1);
}

__global__ __launch_bounds__(256) void scan1(const int* __restrict__ deg,
                                             int* __restrict__ rowptr,
                                             int* __restrict__ bsum) {
    __shared__ int s[256];
    int t = threadIdx.x;
    int i = blockIdx.x * 256 + t;
    int v = (i < NN) ? deg[i] : 0;
    s[t] = v;
    __syncthreads();
    for (int off = 1; off < 256; off <<= 1) {
        int u = (t >= off) ? s[t - off] : 0;
        __syncthreads();
        s[t] += u;
        __syncthreads();
    }
    if (i < NN) rowptr[i] = s[t] - v;
    if (t == 255) bsum[blockIdx.x] = s[255];
}

__global__ __launch_bounds__(256) void scan23(int* __restrict__ rowptr,
                                              const int* __restrict__ bsum) {
    __shared__ int soff;
    const int B = blockIdx.x;
    if (threadIdx.x < 64) {
        int sacc = 0;
        for (int idx = threadIdx.x; idx < B; idx += 64) sacc += bsum[idx];
#pragma unroll
        for (int off = 1; off < 64; off <<= 1) sacc += __shfl_xor(sacc, off);
        if (threadIdx.x == 0) soff = sacc;
    }
    __syncthreads();
    int i = B * 256 + threadIdx.x;
    if (i < NN) rowptr[i] += soff;
    if (i == NN) rowptr[NN] = ETOT;
}

__global__ __launch_bounds__(256) void fillcsr(const int* __restrict__ ei,
                                               const int* __restrict__ rowptr,
                                               const int* __restrict__ epos,
                                               int* __restrict__ csr) {
    int e = blockIdx.x * 256 + threadIdx.x;
    if (e >= ETOT) return;
    int s, d;
    if (e < EE) { s = ei[e]; d = ei[EE + e]; } else { s = d = e - EE; }
    csr[rowptr[d] + epos[e]] = s;
}

// ---------- global max of al2s (1 value) — tiny dispatch, 98 atomics ----------
__global__ __launch_bounds__(256) void maxal2(const float* __restrict__ al2s,
                                              unsigned* __restrict__ gmax2) {
    const int t = blockIdx.x * 256 + threadIdx.x;
    float m = -1e30f;
    for (int i = t; i < NN; i += 98 * 256) m = fmaxf(m, al2s[i]);
#pragma unroll
    for (int off = 32; off; off >>= 1) m = fmaxf(m, __shfl_xor(m, off));
    if ((threadIdx.x & 63) == 0) atomicMax(gmax2, fenc(m));
}

// ---------- fused: layer-1 softmax-aggregate + bias + elu + GEMM2 + al2 ----------
// one wave per dst node (grid-stride); 8 edge-groups x 8 lanes/edge; each lane
// owns one head (8 channels, f16x8 = 16B gather). 8 edges in flight per wave.
__global__ __launch_bounds__(256) void agg1f(const int* __restrict__ rowptr,
                                             const int* __restrict__ csr,
                                             const float* __restrict__ al1s,
                                             const float* __restrict__ al1d,
                                             const unsigned* __restrict__ gmax1,
                                             const __half* __restrict__ h1h,
                                             const float* __restrict__ b1,
                                             const float* __restrict__ W2,
                                             const float* __restrict__ a2s,
                                             const float* __restrict__ a2d,
                                             __half* __restrict__ h2h,
                                             float* __restrict__ al2s,
                                             float* __restrict__ al2d) {
    const int lane = threadIdx.x & 63;
    const int wid  = blockIdx.x * 4 + (threadIdx.x >> 6);
    const int NW   = gridDim.x * 4;
    const int u  = lane & 7;      // head / channel-oct: channels u*8 .. u*8+7
    const int g  = lane >> 3;     // edge group 0..7
    const int c = lane & 31, halfk = lane >> 5;   // epilogue layout
    float w2r[32];
#pragma unroll
    for (int j = 0; j < 32; ++j) w2r[j] = W2[(size_t)(halfk * 32 + j) * 32 + c];
    const float a2sc = a2s[c], a2dc = a2d[c];
    const float4 b1lo = *(const float4*)&b1[u * 8];
    const float4 b1hi = *(const float4*)&b1[u * 8 + 4];
    const float M0 = fdec(gmax1[u]);

    for (int d = wid; d < NN; d += NW) {
        const int beg = rowptr[d], end = rowptr[d + 1];
        const float ald = al1d[d * 8 + u];
        const float M = lrelu(M0 + ald);     // upper bound on this node/head's logits
        float den = 0.f;
        float s0 = 0.f, s1 = 0.f, s2 = 0.f, s3 = 0.f;
        float s4 = 0.f, s5 = 0.f, s6 = 0.f, s7 = 0.f;
        for (int base = beg; base < end; base += 64) {
            int cnt = min(64, end - base);
            int myedge = (base + lane < end) ? csr[base + lane] : 0;
            for (int tt = 0; 8 * tt < cnt; ++tt) {
                int j = 8 * tt + g;
                bool valid = j < cnt;
                int jj = valid ? j : cnt - 1;
                int s = __shfl(myedge, jj);
                float al = al1s[s * 8 + u];
                float4 raw = *(const float4*)&h1h[(size_t)s * 64 + u * 8];  // 16B = 8 halves
                float2 f0 = __half22float2(*(__half2*)&raw.x);
                float2 f1 = __half22float2(*(__half2*)&raw.y);
                float2 f2 = __half22float2(*(__half2*)&raw.z);
                float2 f3 = __half22float2(*(__half2*)&raw.w);
                float a = valid ? __expf(lrelu(al + ald) - M) : 0.f;
                den += a;
                s0 += a * f0.x; s1 += a * f0.y; s2 += a * f1.x; s3 += a * f1.y;
                s4 += a * f2.x; s5 += a * f2.y; s6 += a * f3.x; s7 += a * f3.y;
            }
        }
        // reduce over the 8 edge groups (lane bits 3,4,5)
#pragma unroll
        for (int off = 8; off <= 32; off <<= 1) {
            den += __shfl_xor(den, off);
            s0 += __shfl_xor(s0, off); s1 += __shfl_xor(s1, off);
            s2 += __shfl_xor(s2, off); s3 += __shfl_xor(s3, off);
            s4 += __shfl_xor(s4, off); s5 += __shfl_xor(s5, off);
            s6 += __shfl_xor(s6, off); s7 += __shfl_xor(s7, off);
        }
        const float inv = 1.f / (den + 1e-16f);
        float v0 = s0 * inv + b1lo.x, v1 = s1 * inv + b1lo.y;
        float v2 = s2 * inv + b1lo.z, v3 = s3 * inv + b1lo.w;
        float v4 = s4 * inv + b1hi.x, v5 = s5 * inv + b1hi.y;
        float v6 = s6 * inv + b1hi.z, v7 = s7 * inv + b1hi.w;
        v0 = v0 > 0.f ? v0 : (__expf(v0) - 1.f);
        v1 = v1 > 0.f ? v1 : (__expf(v1) - 1.f);
        v2 = v2 > 0.f ? v2 : (__expf(v2) - 1.f);
        v3 = v3 > 0.f ? v3 : (__expf(v3) - 1.f);
        v4 = v4 > 0.f ? v4 : (__expf(v4) - 1.f);
        v5 = v5 > 0.f ? v5 : (__expf(v5) - 1.f);
        v6 = v6 > 0.f ? v6 : (__expf(v6) - 1.f);
        v7 = v7 > 0.f ? v7 : (__expf(v7) - 1.f);
        // transpose: channel `lane` lives in source lane (lane>>3), element (lane&7)
        int src = lane >> 3;
        float t0 = __shfl(v0, src), t1 = __shfl(v1, src);
        float t2 = __shfl(v2, src), t3 = __shfl(v3, src);
        float t4 = __shfl(v4, src), t5 = __shfl(v5, src);
        float t6 = __shfl(v6, src), t7 = __shfl(v7, src);
        int q = lane & 7;
        float v = (q == 0) ? t0 : (q == 1) ? t1 : (q == 2) ? t2 : (q == 3) ? t3
                : (q == 4) ? t4 : (q == 5) ? t5 : (q == 6) ? t6 : t7;
        // h2 row: 32-step shfl dot
        float acc2 = 0.f;
        const int kb = lane & 32;
#pragma unroll
        for (int j = 0; j < 32; ++j) acc2 += __shfl(v, kb + j) * w2r[j];
        acc2 += __shfl_xor(acc2, 32);
        float ps = acc2 * a2sc, pd = acc2 * a2dc;
#pragma unroll
        for (int off = 1; off < 32; off <<= 1) {
            ps += __shfl_xor(ps, off);
            pd += __shfl_xor(pd, off);
        }
        if (lane == 0) { al2s[d] = ps; al2d[d] = pd; }
        if (halfk == 0) h2h[(size_t)d * 32 + c] = __float2half(acc2);
    }
}

// ---------- layer-2 softmax + aggregate: 16 edge-groups x 4 lanes/edge (f16x8) ----------
__global__ __launch_bounds__(256) void agg2(const int* __restrict__ rowptr,
                                            const int* __restrict__ csr,
                                            const float* __restrict__ al2s,
                                            const float* __restrict__ al2d,
                                            const unsigned* __restrict__ gmax2,
                                            const __half* __restrict__ h2h,
                                            float* __restrict__ out2) {
    const int lane = threadIdx.x & 63;
    const int d = blockIdx.x * 4 + (threadIdx.x >> 6);
    if (d >= NN) return;
    const int u = lane & 3;      // channel-oct: channels u*8 .. u*8+7
    const int g = lane >> 2;     // edge group 0..15
    const int beg = rowptr[d], end = rowptr[d + 1];
    const float ald = al2d[d];
    const float M = lrelu(fdec(gmax2[0]) + ald);
    float den = 0.f;
    float s0 = 0.f, s1 = 0.f, s2 = 0.f, s3 = 0.f;
    float s4 = 0.f, s5 = 0.f, s6 = 0.f, s7 = 0.f;
    for (int base = beg; base < end; base += 64) {
        int cnt = min(64, end - base);
        int myedge = (base + lane < end) ? csr[base + lane] : 0;
        for (int tt = 0; 16 * tt < cnt; ++tt) {
            int j = 16 * tt + g;
            bool valid = j < cnt;
            int jj = valid ? j : cnt - 1;
            int s = __shfl(myedge, jj);
            float al = al2s[s];
            float4 raw = *(const float4*)&h2h[(size_t)s * 32 + u * 8];  // 16B = 8 halves
            float2 f0 = __half22float2(*(__half2*)&raw.x);
            float2 f1 = __half22float2(*(__half2*)&raw.y);
            float2 f2 = __half22float2(*(__half2*)&raw.z);
            float2 f3 = __half22float2(*(__half2*)&raw.w);
            float a = valid ? __expf(lrelu(al + ald) - M) : 0.f;
            den += a;
            s0 += a * f0.x; s1 += a * f0.y; s2 += a * f1.x; s3 += a * f1.y;
            s4 += a * f2.x; s5 += a * f2.y; s6 += a * f3.x; s7 += a * f3.y;
        }
    }
    // reduce over the 16 edge groups (lane bits 2,3,4,5)
#pragma unroll
    for (int off = 4; off <= 32; off <<= 1) {
        den += __shfl_xor(den, off);
        s0 += __shfl_xor(s0, off); s1 += __shfl_xor(s1, off);
        s2 += __shfl_xor(s2, off); s3 += __shfl_xor(s3, off);
        s4 += __shfl_xor(s4, off); s5 += __shfl_xor(s5, off);
        s6 += __shfl_xor(s6, off); s7 += __shfl_xor(s7, off);
    }
    if (g == 0) {
        const float inv = 1.f / (den + 1e-16f);
        *(float4*)&out2[(size_t)d * 32 + u * 8] =
            make_float4(s0 * inv, s1 * inv, s2 * inv, s3 * inv);
        *(float4*)&out2[(size_t)d * 32 + u * 8 + 4] =
            make_float4(s4 * inv, s5 * inv, s6 * inv, s7 * inv);
    }
}

// ---------- pooling (batch sorted -> block-local LDS accumulation) ----------
__global__ __launch_bounds__(256) void pool(const float* __restrict__ out2,
                                            const float* __restrict__ b2,
                                            const int* __restrict__ batch,
                                            float* __restrict__ psum,
                                            float* __restrict__ pcnt) {
    __shared__ float sacc[8][32];
    __shared__ float scnt[8];
    const int t = threadIdx.x;
    const int c = t & 31, sl = t >> 5;
    const int n0 = blockIdx.x * 256;
    const int g0 = batch[n0 < NN ? n0 : NN - 1];
    float acc = 0.f, cnt = 0.f;
    for (int k = 0; k < 32; ++k) {
        int n = n0 + sl + 8 * k;
        if (n < NN) {
            float v = out2[(size_t)n * 32 + c] + b2[c];
            int g = batch[n];
            if (g == g0) {
                acc += v;
                if (c == 0) cnt += 1.f;
            } else {
                atomicAdd(&psum[g * 32 + c], v);
                if (c == 0) atomicAdd(&pcnt[g], 1.f);
            }
        }
    }
    sacc[sl][c] = acc;
    if (c == 0) scnt[sl] = cnt;
    __syncthreads();
    if (t < 32) {
        float s = 0.f;
        for (int j = 0; j < 8; ++j) s += sacc[j][t];
        atomicAdd(&psum[g0 * 32 + t], s);
        if (t == 0) {
            float sc = 0.f;
            for (int j = 0; j < 8; ++j) sc += scnt[j];
            atomicAdd(&pcnt[g0], sc);
        }
    }
}

__global__ __launch_bounds__(128) void final_lin(const float* __restrict__ psum,
                                                 const float* __restrict__ pcnt,
                                                 const float* __restrict__ Wlin,
                                                 const float* __restrict__ blin,
                                                 float* __restrict__ out) {
    int t = threadIdx.x;
    if (t >= NG * 2) return;
    int g = t >> 1, j = t & 1;
    float cnt = fmaxf(pcnt[g], 1.0f);
    float acc = blin[j];
    for (int c = 0; c < 32; ++c) acc += (psum[g * 32 + c] / cnt) * Wlin[c * 2 + j];
    out[g * 2 + j] = acc;
}

// ---------- launch ----------
static inline size_t alignup(size_t x) { return (x + 255) & ~(size_t)255; }

extern "C" void kernel_launch(void* const* d_in, const int* in_sizes, int n_in,
                              void* d_out, int out_size, void* d_ws, size_t ws_size,
                              hipStream_t stream) {
    const float* x    = (const float*)d_in[0];
    const int*   ei   = (const int*)d_in[1];
    const int*   batch= (const int*)d_in[2];
    const float* W1   = (const float*)d_in[3];
    const float* a1s  = (const float*)d_in[4];
    const float* a1d  = (const float*)d_in[5];
    const float* b1   = (const float*)d_in[6];
    const float* W2   = (const float*)d_in[7];
    const float* a2s  = (const float*)d_in[8];
    const float* a2d  = (const float*)d_in[9];
    const float* b2   = (const float*)d_in[10];
    const float* Wlin = (const float*)d_in[11];
    const float* blin = (const float*)d_in[12];
    float* out = (float*)d_out;
    char* ws = (char*)d_ws;
    (void)in_sizes; (void)n_in; (void)out_size; (void)ws_size;

    size_t o = 0;
    // ---- zeroed region ----
    size_t DEG  = o; o += alignup((size_t)NN * 4);
    size_t PSUM = o; o += alignup((size_t)NG * 32 * 4);
    size_t PCNT = o; o += alignup((size_t)NG * 4);
    size_t GMX1 = o; o += alignup(8 * 4);
    size_t GMX2 = o; o += alignup(4);
    size_t zero_bytes = o;
    // ---- overwritten region ----
    size_t ROWP = o; o += alignup((size_t)(NN + 1) * 4);
    size_t BSUM = o; o += alignup((size_t)256 * 4);
    size_t EPOS = o; o += alignup((size_t)ETOT * 4);
    size_t CSR  = o; o += alignup((size_t)ETOT * 4 + 256);  // +slack for benign OOB lane reads
    size_t H1H  = o; o += alignup((size_t)NN * 64 * 2);     // f16
    size_t AL1S = o; o += alignup((size_t)NN * 8 * 4);
    size_t AL1D = o; o += alignup((size_t)NN * 8 * 4);
    size_t H2H  = o; o += alignup((size_t)NN * 32 * 2);     // f16
    size_t AL2S = o; o += alignup((size_t)NN * 4);
    size_t AL2D = o; o += alignup((size_t)NN * 4);
    size_t OUT2 = o; o += alignup((size_t)NN * 32 * 4);

    int*      deg    = (int*)(ws + DEG);
    float*    psum   = (float*)(ws + PSUM);
    float*    pcnt   = (float*)(ws + PCNT);
    unsigned* gmax1  = (unsigned*)(ws + GMX1);
    unsigned* gmax2  = (unsigned*)(ws + GMX2);
    int*      rowptr = (int*)(ws + ROWP);
    int*      bsum   = (int*)(ws + BSUM);
    int*      epos   = (int*)(ws + EPOS);
    int*      csr    = (int*)(ws + CSR);
    __half*   h1h    = (__half*)(ws + H1H);
    float*    al1s_  = (float*)(ws + AL1S);
    float*    al1d_  = (float*)(ws + AL1D);
    __half*   h2h    = (__half*)(ws + H2H);
    float*    al2s   = (float*)(ws + AL2S);
    float*    al2d   = (float*)(ws + AL2D);
    float*    out2   = (float*)(ws + OUT2);

    hipMemsetAsync(ws, 0, zero_bytes, stream);

    gemm1<<<(NN + 63) / 64, 256, 0, stream>>>(x, W1, a1s, a1d, h1h, al1s_, al1d_);

    const int gE = (ETOT + 255) / 256;
    const int nbScan = (NN + 255) / 256;          // 196
    hist<<<gE, 256, 0, stream>>>(ei, deg, epos);
    scan1<<<nbScan, 256, 0, stream>>>(deg, rowptr, bsum);
    scan23<<<(NN + 256) / 256, 256, 0, stream>>>(rowptr, bsum);
    fillcsr<<<gE, 256, 0, stream>>>(ei, rowptr, epos, csr);

    maxal1<<<98, 256, 0, stream>>>(al1s_, gmax1);

    agg1f<<<2048, 256, 0, stream>>>(rowptr, csr, al1s_, al1d_, gmax1, h1h,
                                    b1, W2, a2s, a2d, h2h, al2s, al2d);

    maxal2<<<98, 256, 0, stream>>>(al2s, gmax2);

    const int gN = (NN + 3) / 4;
    agg2<<<gN, 256, 0, stream>>>(rowptr, csr, al2s, al2d, gmax2, h2h, out2);

    pool<<<(NN + 255) / 256, 256, 0, stream>>>(out2, b2, batch, psum, pcnt);

    final_lin<<<1, 128, 0, stream>>>(psum, pcnt, Wlin, blin, out);
}

// Round 16
// 223.630 us; speedup vs baseline: 1.0793x; 1.0793x over previous
//
#include <hip/hip_runtime.h>
#include <hip/hip_fp16.h>

#define NN 50000
#define EE 800000
#define ETOT (EE + NN)     // edges + self-loops
#define NEG 0.2f
#define NG 64
#define HISTB 256          // hist blocks fused into gemm1h
#define MAXB 98            // maxal1 blocks fused into fillmax

__device__ __forceinline__ float lrelu(float x) { return x > 0.f ? x : NEG * x; }
__device__ __forceinline__ unsigned fenc(float f) {
    unsigned u = __float_as_uint(f);
    return (u & 0x80000000u) ? ~u : (u | 0x80000000u);
}
__device__ __forceinline__ float fdec(unsigned u) {
    return (u & 0x80000000u) ? __uint_as_float(u & 0x7fffffffu)
                             : __uint_as_float(~u);
}

// ---------- fused: GEMM1 (h1=x@W1, f16 out; al1 halves f32) + edge histogram ----------
// blocks [0,HISTB): hist over edges (independent of GEMM inputs; overlaps).
// blocks [HISTB, HISTB+782): 64x64 GEMM tiles.
__global__ __launch_bounds__(256) void gemm1h(const float* __restrict__ x,
                                              const float* __restrict__ W1,
                                              const float* __restrict__ a1s,
                                              const float* __restrict__ a1d,
                                              __half* __restrict__ h1h,
                                              float* __restrict__ al1s,
                                              float* __restrict__ al1d,
                                              const int* __restrict__ ei,
                                              int* __restrict__ deg,
                                              unsigned short* __restrict__ epos) {
    __shared__ float sx[64][132];   // row stride 528B (16B-aligned)
    __shared__ float sW[64][64];
    const int t = threadIdx.x;
    if (blockIdx.x < HISTB) {
        // ---- hist part: epos[e] = slot of edge e within dst bucket ----
        for (long long e = (long long)blockIdx.x * 256 + t; e < ETOT; e += (long long)HISTB * 256) {
            int d = (e < EE) ? ei[EE + e] : (int)(e - EE);
            epos[e] = (unsigned short)atomicAdd(&deg[d], 1);
        }
        return;
    }
    const int row0 = (blockIdx.x - HISTB) * 64;
    for (int i = t * 4; i < 64 * 128; i += 256 * 4) {
        int r = i >> 7, k = i & 127;
        int gr = row0 + r;
        float4 v = make_float4(0.f, 0.f, 0.f, 0.f);
        if (gr < NN) v = *(const float4*)&x[(size_t)gr * 128 + k];
        *(float4*)&sx[r][k] = v;
    }
    float acc[4][4] = {{0.f, 0.f, 0.f, 0.f}};
    const int c4 = (t & 15) * 4;
    const int r4 = (t >> 4) * 4;
    for (int k0 = 0; k0 < 128; k0 += 64) {
        __syncthreads();
        for (int i = t * 4; i < 64 * 64; i += 256 * 4) {
            int kk = i >> 6, c = i & 63;
            *(float4*)&sW[kk][c] = *(const float4*)&W1[(size_t)(k0 + kk) * 64 + c];
        }
        __syncthreads();
#pragma unroll 4
        for (int kk = 0; kk < 64; kk += 4) {
            float4 wv0 = *(float4*)&sW[kk + 0][c4];
            float4 wv1 = *(float4*)&sW[kk + 1][c4];
            float4 wv2 = *(float4*)&sW[kk + 2][c4];
            float4 wv3 = *(float4*)&sW[kk + 3][c4];
#pragma unroll
            for (int r = 0; r < 4; ++r) {
                float4 xv = *(const float4*)&sx[r4 + r][k0 + kk];
                acc[r][0] += xv.x * wv0.x; acc[r][1] += xv.x * wv0.y; acc[r][2] += xv.x * wv0.z; acc[r][3] += xv.x * wv0.w;
                acc[r][0] += xv.y * wv1.x; acc[r][1] += xv.y * wv1.y; acc[r][2] += xv.y * wv1.z; acc[r][3] += xv.y * wv1.w;
                acc[r][0] += xv.z * wv2.x; acc[r][1] += xv.z * wv2.y; acc[r][2] += xv.z * wv2.z; acc[r][3] += xv.z * wv2.w;
                acc[r][0] += xv.w * wv3.x; acc[r][1] += xv.w * wv3.y; acc[r][2] += xv.w * wv3.z; acc[r][3] += xv.w * wv3.w;
            }
        }
    }
    const float4 asv = *(const float4*)&a1s[c4];
    const float4 adv = *(const float4*)&a1d[c4];
#pragma unroll
    for (int r = 0; r < 4; ++r) {
        int row = row0 + r4 + r;
        float ps = acc[r][0] * asv.x + acc[r][1] * asv.y + acc[r][2] * asv.z + acc[r][3] * asv.w;
        float pd = acc[r][0] * adv.x + acc[r][1] * adv.y + acc[r][2] * adv.z + acc[r][3] * adv.w;
        ps += __shfl_xor(ps, 1);     // pair covers one head (8 channels)
        pd += __shfl_xor(pd, 1);
        if (row < NN) {
            __half2 h01 = __floats2half2_rn(acc[r][0], acc[r][1]);
            __half2 h23 = __floats2half2_rn(acc[r][2], acc[r][3]);
            float2 pk;
            *(__half2*)&pk.x = h01;
            *(__half2*)&pk.y = h23;
            *(float2*)&h1h[(size_t)row * 64 + c4] = pk;   // 8B store
            if ((t & 1) == 0) {
                int h = (t & 15) >> 1;
                al1s[row * 8 + h] = ps;
                al1d[row * 8 + h] = pd;
            }
        }
    }
}

// ---------- scan ----------
__global__ __launch_bounds__(256) void scan1(const int* __restrict__ deg,
                                             int* __restrict__ rowptr,
                                             int* __restrict__ bsum) {
    __shared__ int s[256];
    int t = threadIdx.x;
    int i = blockIdx.x * 256 + t;
    int v = (i < NN) ? deg[i] : 0;
    s[t] = v;
    __syncthreads();
    for (int off = 1; off < 256; off <<= 1) {
        int u = (t >= off) ? s[t - off] : 0;
        __syncthreads();
        s[t] += u;
        __syncthreads();
    }
    if (i < NN) rowptr[i] = s[t] - v;
    if (t == 255) bsum[blockIdx.x] = s[255];
}

__global__ __launch_bounds__(256) void scan23(int* __restrict__ rowptr,
                                              const int* __restrict__ bsum) {
    __shared__ int soff;
    const int B = blockIdx.x;
    if (threadIdx.x < 64) {
        int sacc = 0;
        for (int idx = threadIdx.x; idx < B; idx += 64) sacc += bsum[idx];
#pragma unroll
        for (int off = 1; off < 64; off <<= 1) sacc += __shfl_xor(sacc, off);
        if (threadIdx.x == 0) soff = sacc;
    }
    __syncthreads();
    int i = B * 256 + threadIdx.x;
    if (i < NN) rowptr[i] += soff;
    if (i == NN) rowptr[NN] = ETOT;
}

// ---------- fused: maxal1 (blocks [0,MAXB)) + fillcsr (rest) ----------
__global__ __launch_bounds__(256) void fillmax(const int* __restrict__ ei,
                                               const int* __restrict__ rowptr,
                                               const unsigned short* __restrict__ epos,
                                               unsigned short* __restrict__ csr,
                                               const float* __restrict__ al1s,
                                               unsigned* __restrict__ gmax1) {
    if (blockIdx.x < MAXB) {
        const int t = blockIdx.x * 256 + threadIdx.x;
        const int h = t & 7;
        float m = -1e30f;
        for (int i = t; i < NN * 8; i += MAXB * 256) m = fmaxf(m, al1s[i]);
        m = fmaxf(m, __shfl_xor(m, 8));
        m = fmaxf(m, __shfl_xor(m, 16));
        m = fmaxf(m, __shfl_xor(m, 32));
        if ((threadIdx.x & 63) < 8) atomicMax(&gmax1[h], fenc(m));
        return;
    }
    int e = (blockIdx.x - MAXB) * 256 + threadIdx.x;
    if (e >= ETOT) return;
    int s, d;
    if (e < EE) { s = ei[e]; d = ei[EE + e]; } else { s = d = e - EE; }
    csr[rowptr[d] + epos[e]] = (unsigned short)s;
}

// ---------- global max of al2s (1 value) — tiny dispatch, 98 atomics ----------
__global__ __launch_bounds__(256) void maxal2(const float* __restrict__ al2s,
                                              unsigned* __restrict__ gmax2) {
    const int t = blockIdx.x * 256 + threadIdx.x;
    float m = -1e30f;
    for (int i = t; i < NN; i += 98 * 256) m = fmaxf(m, al2s[i]);
#pragma unroll
    for (int off = 32; off; off >>= 1) m = fmaxf(m, __shfl_xor(m, off));
    if ((threadIdx.x & 63) == 0) atomicMax(gmax2, fenc(m));
}

// ---------- fused: layer-1 softmax-aggregate + bias + elu + GEMM2 + al2 ----------
// R14-proven structure: 4 edge-groups x 16 chan-quads; f16 8B gathers; u16 csr.
__global__ __launch_bounds__(256) void agg1f(const int* __restrict__ rowptr,
                                             const unsigned short* __restrict__ csr,
                                             const float* __restrict__ al1s,
                                             const float* __restrict__ al1d,
                                             const unsigned* __restrict__ gmax1,
                                             const __half* __restrict__ h1h,
                                             const float* __restrict__ b1,
                                             const float* __restrict__ W2,
                                             const float* __restrict__ a2s,
                                             const float* __restrict__ a2d,
                                             __half* __restrict__ h2h,
                                             float* __restrict__ al2s,
                                             float* __restrict__ al2d) {
    const int lane = threadIdx.x & 63;
    const int wid  = blockIdx.x * 4 + (threadIdx.x >> 6);
    const int NW   = gridDim.x * 4;
    const int u  = lane & 15;     // channel-quad: channels u*4 .. u*4+3
    const int g  = lane >> 4;     // edge group 0..3
    const int hh = u >> 1;        // head of this channel-quad
    const int c = lane & 31, halfk = lane >> 5;   // epilogue layout
    float w2r[32];
#pragma unroll
    for (int j = 0; j < 32; ++j) w2r[j] = W2[(size_t)(halfk * 32 + j) * 32 + c];
    const float a2sc = a2s[c], a2dc = a2d[c];
    const float4 b14 = *(const float4*)&b1[u * 4];
    const float M0 = fdec(gmax1[hh]);

    for (int d = wid; d < NN; d += NW) {
        const int beg = rowptr[d], end = rowptr[d + 1];
        const float ald = al1d[d * 8 + hh];
        const float M = lrelu(M0 + ald);     // upper bound on this node/head's logits
        float den = 0.f;
        float4 a4 = make_float4(0.f, 0.f, 0.f, 0.f);
        for (int base = beg; base < end; base += 64) {
            int cnt = min(64, end - base);
            int myedge = (base + lane < end) ? (int)csr[base + lane] : 0;
            for (int tt = 0; 4 * tt < cnt; ++tt) {
                int j = 4 * tt + g;
                bool valid = j < cnt;
                int jj = valid ? j : cnt - 1;
                int s = __shfl(myedge, jj);
                float al = al1s[s * 8 + hh];
                float2 raw = *(const float2*)&h1h[(size_t)s * 64 + u * 4];  // 8B gather
                float2 f01 = __half22float2(*(__half2*)&raw.x);
                float2 f23 = __half22float2(*(__half2*)&raw.y);
                float a = valid ? __expf(lrelu(al + ald) - M) : 0.f;
                den += a;
                a4.x += a * f01.x; a4.y += a * f01.y;
                a4.z += a * f23.x; a4.w += a * f23.y;
            }
        }
        // reduce over the 4 edge groups (lane bits 4,5)
        den += __shfl_xor(den, 16); den += __shfl_xor(den, 32);
        a4.x += __shfl_xor(a4.x, 16); a4.x += __shfl_xor(a4.x, 32);
        a4.y += __shfl_xor(a4.y, 16); a4.y += __shfl_xor(a4.y, 32);
        a4.z += __shfl_xor(a4.z, 16); a4.z += __shfl_xor(a4.z, 32);
        a4.w += __shfl_xor(a4.w, 16); a4.w += __shfl_xor(a4.w, 32);
        const float inv = 1.f / (den + 1e-16f);
        float4 v4;
        v4.x = a4.x * inv + b14.x; v4.y = a4.y * inv + b14.y;
        v4.z = a4.z * inv + b14.z; v4.w = a4.w * inv + b14.w;
        v4.x = v4.x > 0.f ? v4.x : (__expf(v4.x) - 1.f);
        v4.y = v4.y > 0.f ? v4.y : (__expf(v4.y) - 1.f);
        v4.z = v4.z > 0.f ? v4.z : (__expf(v4.z) - 1.f);
        v4.w = v4.w > 0.f ? v4.w : (__expf(v4.w) - 1.f);
        // transpose: lane picks up scalar channel `lane`
        float t0 = __shfl(v4.x, lane >> 2);
        float t1 = __shfl(v4.y, lane >> 2);
        float t2 = __shfl(v4.z, lane >> 2);
        float t3 = __shfl(v4.w, lane >> 2);
        int q = lane & 3;
        float v = (q == 0) ? t0 : (q == 1) ? t1 : (q == 2) ? t2 : t3;
        // h2 row: 32-step shfl dot
        float acc2 = 0.f;
        const int kb = lane & 32;
#pragma unroll
        for (int j = 0; j < 32; ++j) acc2 += __shfl(v, kb + j) * w2r[j];
        acc2 += __shfl_xor(acc2, 32);
        float ps = acc2 * a2sc, pd = acc2 * a2dc;
#pragma unroll
        for (int off = 1; off < 32; off <<= 1) {
            ps += __shfl_xor(ps, off);
            pd += __shfl_xor(pd, off);
        }
        if (lane == 0) { al2s[d] = ps; al2d[d] = pd; }
        if (halfk == 0) h2h[(size_t)d * 32 + c] = __float2half(acc2);
    }
}

// ---------- layer-2 softmax + aggregate: 8 edge-groups x 8 chan-quads (R14 form) ----------
__global__ __launch_bounds__(256) void agg2(const int* __restrict__ rowptr,
                                            const unsigned short* __restrict__ csr,
                                            const float* __restrict__ al2s,
                                            const float* __restrict__ al2d,
                                            const unsigned* __restrict__ gmax2,
                                            const __half* __restrict__ h2h,
                                            float* __restrict__ out2) {
    const int lane = threadIdx.x & 63;
    const int d = blockIdx.x * 4 + (threadIdx.x >> 6);
    if (d >= NN) return;
    const int u = lane & 7;      // channel-quad
    const int g = lane >> 3;     // edge group 0..7
    const int beg = rowptr[d], end = rowptr[d + 1];
    const float ald = al2d[d];
    const float M = lrelu(fdec(gmax2[0]) + ald);
    float den = 0.f;
    float4 a4 = make_float4(0.f, 0.f, 0.f, 0.f);
    for (int base = beg; base < end; base += 64) {
        int cnt = min(64, end - base);
        int myedge = (base + lane < end) ? (int)csr[base + lane] : 0;
        for (int tt = 0; 8 * tt < cnt; ++tt) {
            int j = 8 * tt + g;
            bool valid = j < cnt;
            int jj = valid ? j : cnt - 1;
            int s = __shfl(myedge, jj);
            float al = al2s[s];
            float2 raw = *(const float2*)&h2h[(size_t)s * 32 + u * 4];  // 8B gather
            float2 f01 = __half22float2(*(__half2*)&raw.x);
            float2 f23 = __half22float2(*(__half2*)&raw.y);
            float a = valid ? __expf(lrelu(al + ald) - M) : 0.f;
            den += a;
            a4.x += a * f01.x; a4.y += a * f01.y;
            a4.z += a * f23.x; a4.w += a * f23.y;
        }
    }
    den += __shfl_xor(den, 8); den += __shfl_xor(den, 16); den += __shfl_xor(den, 32);
    a4.x += __shfl_xor(a4.x, 8); a4.x += __shfl_xor(a4.x, 16); a4.x += __shfl_xor(a4.x, 32);
    a4.y += __shfl_xor(a4.y, 8); a4.y += __shfl_xor(a4.y, 16); a4.y += __shfl_xor(a4.y, 32);
    a4.z += __shfl_xor(a4.z, 8); a4.z += __shfl_xor(a4.z, 16); a4.z += __shfl_xor(a4.z, 32);
    a4.w += __shfl_xor(a4.w, 8); a4.w += __shfl_xor(a4.w, 16); a4.w += __shfl_xor(a4.w, 32);
    if (g == 0) {
        const float inv = 1.f / (den + 1e-16f);
        *(float4*)&out2[(size_t)d * 32 + u * 4] =
            make_float4(a4.x * inv, a4.y * inv, a4.z * inv, a4.w * inv);
    }
}

// ---------- pooling (batch sorted -> block-local LDS accumulation) ----------
__global__ __launch_bounds__(256) void pool(const float* __restrict__ out2,
                                            const float* __restrict__ b2,
                                            const int* __restrict__ batch,
                                            float* __restrict__ psum,
                                            float* __restrict__ pcnt) {
    __shared__ float sacc[8][32];
    __shared__ float scnt[8];
    const int t = threadIdx.x;
    const int c = t & 31, sl = t >> 5;
    const int n0 = blockIdx.x * 256;
    const int g0 = batch[n0 < NN ? n0 : NN - 1];
    float acc = 0.f, cnt = 0.f;
    for (int k = 0; k < 32; ++k) {
        int n = n0 + sl + 8 * k;
        if (n < NN) {
            float v = out2[(size_t)n * 32 + c] + b2[c];
            int g = batch[n];
            if (g == g0) {
                acc += v;
                if (c == 0) cnt += 1.f;
            } else {
                atomicAdd(&psum[g * 32 + c], v);
                if (c == 0) atomicAdd(&pcnt[g], 1.f);
            }
        }
    }
    sacc[sl][c] = acc;
    if (c == 0) scnt[sl] = cnt;
    __syncthreads();
    if (t < 32) {
        float s = 0.f;
        for (int j = 0; j < 8; ++j) s += sacc[j][t];
        atomicAdd(&psum[g0 * 32 + t], s);
        if (t == 0) {
            float sc = 0.f;
            for (int j = 0; j < 8; ++j) sc += scnt[j];
            atomicAdd(&pcnt[g0], sc);
        }
    }
}

__global__ __launch_bounds__(128) void final_lin(const float* __restrict__ psum,
                                                 const float* __restrict__ pcnt,
                                                 const float* __restrict__ Wlin,
                                                 const float* __restrict__ blin,
                                                 float* __restrict__ out) {
    int t = threadIdx.x;
    if (t >= NG * 2) return;
    int g = t >> 1, j = t & 1;
    float cnt = fmaxf(pcnt[g], 1.0f);
    float acc = blin[j];
    for (int c = 0; c < 32; ++c) acc += (psum[g * 32 + c] / cnt) * Wlin[c * 2 + j];
    out[g * 2 + j] = acc;
}

// ---------- launch ----------
static inline size_t alignup(size_t x) { return (x + 255) & ~(size_t)255; }

extern "C" void kernel_launch(void* const* d_in, const int* in_sizes, int n_in,
                              void* d_out, int out_size, void* d_ws, size_t ws_size,
                              hipStream_t stream) {
    const float* x    = (const float*)d_in[0];
    const int*   ei   = (const int*)d_in[1];
    const int*   batch= (const int*)d_in[2];
    const float* W1   = (const float*)d_in[3];
    const float* a1s  = (const float*)d_in[4];
    const float* a1d  = (const float*)d_in[5];
    const float* b1   = (const float*)d_in[6];
    const float* W2   = (const float*)d_in[7];
    const float* a2s  = (const float*)d_in[8];
    const float* a2d  = (const float*)d_in[9];
    const float* b2   = (const float*)d_in[10];
    const float* Wlin = (const float*)d_in[11];
    const float* blin = (const float*)d_in[12];
    float* out = (float*)d_out;
    char* ws = (char*)d_ws;
    (void)in_sizes; (void)n_in; (void)out_size; (void)ws_size;

    size_t o = 0;
    // ---- zeroed region ----
    size_t DEG  = o; o += alignup((size_t)NN * 4);
    size_t PSUM = o; o += alignup((size_t)NG * 32 * 4);
    size_t PCNT = o; o += alignup((size_t)NG * 4);
    size_t GMX1 = o; o += alignup(8 * 4);
    size_t GMX2 = o; o += alignup(4);
    size_t zero_bytes = o;
    // ---- overwritten region ----
    size_t ROWP = o; o += alignup((size_t)(NN + 1) * 4);
    size_t BSUM = o; o += alignup((size_t)256 * 4);
    size_t EPOS = o; o += alignup((size_t)ETOT * 2);        // u16
    size_t CSR  = o; o += alignup((size_t)ETOT * 2 + 256);  // u16 (+slack)
    size_t H1H  = o; o += alignup((size_t)NN * 64 * 2);     // f16
    size_t AL1S = o; o += alignup((size_t)NN * 8 * 4);
    size_t AL1D = o; o += alignup((size_t)NN * 8 * 4);
    size_t H2H  = o; o += alignup((size_t)NN * 32 * 2);     // f16
    size_t AL2S = o; o += alignup((size_t)NN * 4);
    size_t AL2D = o; o += alignup((size_t)NN * 4);
    size_t OUT2 = o; o += alignup((size_t)NN * 32 * 4);

    int*            deg    = (int*)(ws + DEG);
    float*          psum   = (float*)(ws + PSUM);
    float*          pcnt   = (float*)(ws + PCNT);
    unsigned*       gmax1  = (unsigned*)(ws + GMX1);
    unsigned*       gmax2  = (unsigned*)(ws + GMX2);
    int*            rowptr = (int*)(ws + ROWP);
    int*            bsum   = (int*)(ws + BSUM);
    unsigned short* epos   = (unsigned short*)(ws + EPOS);
    unsigned short* csr    = (unsigned short*)(ws + CSR);
    __half*         h1h    = (__half*)(ws + H1H);
    float*          al1s_  = (float*)(ws + AL1S);
    float*          al1d_  = (float*)(ws + AL1D);
    __half*         h2h    = (__half*)(ws + H2H);
    float*          al2s   = (float*)(ws + AL2S);
    float*          al2d   = (float*)(ws + AL2D);
    float*          out2   = (float*)(ws + OUT2);

    hipMemsetAsync(ws, 0, zero_bytes, stream);

    const int gemmB = (NN + 63) / 64;            // 782
    gemm1h<<<HISTB + gemmB, 256, 0, stream>>>(x, W1, a1s, a1d, h1h, al1s_, al1d_,
                                              ei, deg, epos);

    const int nbScan = (NN + 255) / 256;          // 196
    scan1<<<nbScan, 256, 0, stream>>>(deg, rowptr, bsum);
    scan23<<<(NN + 256) / 256, 256, 0, stream>>>(rowptr, bsum);

    const int gE = (ETOT + 255) / 256;            // 3321
    fillmax<<<MAXB + gE, 256, 0, stream>>>(ei, rowptr, epos, csr, al1s_, gmax1);

    agg1f<<<2048, 256, 0, stream>>>(rowptr, csr, al1s_, al1d_, gmax1, h1h,
                                    b1, W2, a2s, a2d, h2h, al2s, al2d);

    maxal2<<<98, 256, 0, stream>>>(al2s, gmax2);

    const int gN = (NN + 3) / 4;
    agg2<<<gN, 256, 0, stream>>>(rowptr, csr, al2s, al2d, gmax2, h2h, out2);

    pool<<<(NN + 255) / 256, 256, 0, stream>>>(out2, b2, batch, psum, pcnt);

    final_lin<<<1, 128, 0, stream>>>(psum, pcnt, Wlin, blin, out);
}